// Round 9
// baseline (190.411 us; speedup 1.0000x reference)
//
#include <hip/hip_runtime.h>

// Linformer head, MFMA bf16-split rewrite. B=16, S=4096, D=64, KP=256.
// R3: frag-contiguous Kp/Vp tables + coalesced attn stores.
// R4: attn B-operands LDS-staged once per block.
// R5: wcvt frag-tile W layout + proj W reg-dbuf, 8x512 s-chunks (179.4us total;
//     proven best config: proj (512,2), reduce-8).
// R6/R8: proj restructures + reduce-16 regressed (+10us) -> REVERTED.
// R9: attn staging reschedule (T14 done right: __syncthreads drains vmcnt, so
//     loads must be issued AFTER the barrier they'd otherwise drain at):
//     - kd0 Kp hi/lo loads at kernel start, hidden under Q f2bf VALU work.
//     - A-frags (both kd) hoisted to regs; Qf region then reused as kd1-hi
//       buffer: loads issued post-bar, LDS-written after kd0's 48 MFMAs.
//     - kd1-lo operand read directly from L2 (dense 1KB/wave frag-order loads
//       pipelined with MFMAs) -> staged bytes halved, one stage phase removed.
//     - V batch1 loads issued after the PV-entry barrier (covered by PV1).

#define B_  16
#define S_  4096
#define D_  64
#define KP_ 256

typedef short v8s __attribute__((ext_vector_type(8)));
typedef float v4f __attribute__((ext_vector_type(4)));

__device__ __forceinline__ short f2bf(float x) {        // RNE f32 -> bf16
    union { float f; unsigned u; } v; v.f = x;
    unsigned r = v.u + 0x7FFFu + ((v.u >> 16) & 1u);
    return (short)(r >> 16);
}
__device__ __forceinline__ float bf2f(short h) {
    union { float f; unsigned u; } v; v.u = ((unsigned)(unsigned short)h) << 16;
    return v.f;
}

// ---------------------------------------------------------------------------
// Kernel 1: W fp32 -> bf16 hi/lo planes in FRAG-TILE order. grid (1024,2)x256.
// ---------------------------------------------------------------------------
__global__ __launch_bounds__(256)
void wcvt_kernel(const float* __restrict__ E_w, const float* __restrict__ F_w,
                 short* __restrict__ Whi, short* __restrict__ Wlo)
{
    const int p = blockIdx.y;
    const float* W = p ? F_w : E_w;
    const size_t i4 = (size_t)blockIdx.x * 256 + threadIdx.x;   // float4 idx
    float4 v = ((const float4*)W)[i4];
    short4 h, lo;
    h.x = f2bf(v.x); lo.x = f2bf(v.x - bf2f(h.x));
    h.y = f2bf(v.y); lo.y = f2bf(v.y - bf2f(h.y));
    h.z = f2bf(v.z); lo.z = f2bf(v.z - bf2f(h.z));
    h.w = f2bf(v.w); lo.w = f2bf(v.w - bf2f(h.w));
    const int k  = (int)(i4 >> 10);            // S/4 = 1024 float4 per k-row
    const int s0 = (int)(i4 & 1023) << 2;      // s0 % 4 == 0 -> same 8-block
    const size_t fo = (((size_t)p * 16 + (k >> 4)) * 128 + (s0 >> 5)) * 512
                    + (size_t)(((k & 15) + ((s0 >> 3) & 3) * 16) * 8) + (s0 & 7);
    *(short4*)(Whi + fo) = h;
    *(short4*)(Wlo + fo) = lo;
}

// ---------------------------------------------------------------------------
// Kernel 2: projections via MFMA, split-S partials. (R5 exact, 179.4us config)
// grid (sc 8, p 2, b 16) x 512 thr. W loads frag-tile dense + reg double-buffered.
// ---------------------------------------------------------------------------
__global__ __launch_bounds__(512, 2)
void proj_mfma_kernel(const float* __restrict__ Kg, const float* __restrict__ Vg,
                      const short* __restrict__ Whi, const short* __restrict__ Wlo,
                      float* __restrict__ PpartK, float* __restrict__ PpartV)
{
    const int sc = blockIdx.x;     // s-chunk of 512
    const int p  = blockIdx.y;     // 0 -> Kp, 1 -> Vp
    const int b  = blockIdx.z;

    const float* src = (p ? Vg : Kg) + ((size_t)b * S_ + sc * 512) * D_;

    __shared__ __align__(16) short Af[2][2][4][512];  // [buf][plane][mt=d/16][fraglane*8] 16KB

    const int t  = threadIdx.x;
    const int wv = t >> 6;
    const int l  = t & 63;
    const int k16 = wv * 2;        // wave's base k16 tile

    const size_t wbase = ((size_t)p * 16 + k16) * 128 * 512 + (size_t)(sc * 16) * 512 + (size_t)l * 8;

    v4f acc[2][4];
#pragma unroll
    for (int i = 0; i < 2; ++i)
#pragma unroll
        for (int m = 0; m < 4; ++m) acc[i][m] = (v4f){0.f, 0.f, 0.f, 0.f};

    const bool do_stage = (t < 256);
    const int sd   = t & 63;
    const int soct = (t >> 6) & 3;
    const int smt  = sd >> 4;
    const int sfl  = (sd & 15) + soct * 16;

    v8s whA[2], wlA[2], whB[2], wlB[2];
#pragma unroll
    for (int i = 0; i < 2; ++i) {
        size_t o = wbase + (size_t)i * 65536;
        whA[i] = *(const v8s*)(Whi + o);
        wlA[i] = *(const v8s*)(Wlo + o);
    }

    float g[8];
    if (do_stage) {
        const float* sp = src + (size_t)(soct * 8) * D_ + sd;
#pragma unroll
        for (int j = 0; j < 8; ++j) g[j] = sp[(size_t)j * D_];
        v8s hi, lo;
#pragma unroll
        for (int j = 0; j < 8; ++j) { short h = f2bf(g[j]); hi[j] = h; lo[j] = f2bf(g[j] - bf2f(h)); }
        *(v8s*)&Af[0][0][smt][sfl * 8] = hi;
        *(v8s*)&Af[0][1][smt][sfl * 8] = lo;
    }
    __syncthreads();

    auto step = [&](int st, v8s (&whc)[2], v8s (&wlc)[2], v8s (&whn)[2], v8s (&wln)[2]) {
        const int cur = st & 1;
        if (st + 1 < 16) {
#pragma unroll
            for (int i = 0; i < 2; ++i) {
                size_t o = wbase + (size_t)i * 65536 + (size_t)(st + 1) * 512;
                whn[i] = *(const v8s*)(Whi + o);
                wln[i] = *(const v8s*)(Wlo + o);
            }
            if (do_stage) {
                const float* sp = src + (size_t)((st + 1) * 32 + soct * 8) * D_ + sd;
#pragma unroll
                for (int j = 0; j < 8; ++j) g[j] = sp[(size_t)j * D_];
            }
        }
        v8s sh[4], sl[4];
#pragma unroll
        for (int m = 0; m < 4; ++m) {
            sh[m] = *(const v8s*)&Af[cur][0][m][l * 8];
            sl[m] = *(const v8s*)&Af[cur][1][m][l * 8];
        }
        if (p == 0) {       // C[k,d] = W @ src : A=W, B=src
#pragma unroll
            for (int i = 0; i < 2; ++i)
#pragma unroll
                for (int m = 0; m < 4; ++m) {
                    acc[i][m] = __builtin_amdgcn_mfma_f32_16x16x32_bf16(whc[i], sh[m], acc[i][m], 0, 0, 0);
                    acc[i][m] = __builtin_amdgcn_mfma_f32_16x16x32_bf16(whc[i], sl[m], acc[i][m], 0, 0, 0);
                    acc[i][m] = __builtin_amdgcn_mfma_f32_16x16x32_bf16(wlc[i], sh[m], acc[i][m], 0, 0, 0);
                }
        } else {            // C'[d,k] = src^T @ W^T : A=src, B=W
#pragma unroll
            for (int i = 0; i < 2; ++i)
#pragma unroll
                for (int m = 0; m < 4; ++m) {
                    acc[i][m] = __builtin_amdgcn_mfma_f32_16x16x32_bf16(sh[m], whc[i], acc[i][m], 0, 0, 0);
                    acc[i][m] = __builtin_amdgcn_mfma_f32_16x16x32_bf16(sl[m], whc[i], acc[i][m], 0, 0, 0);
                    acc[i][m] = __builtin_amdgcn_mfma_f32_16x16x32_bf16(sh[m], wlc[i], acc[i][m], 0, 0, 0);
                }
        }
        if (st + 1 < 16 && do_stage) {
            v8s hi, lo;
#pragma unroll
            for (int j = 0; j < 8; ++j) { short h = f2bf(g[j]); hi[j] = h; lo[j] = f2bf(g[j] - bf2f(h)); }
            *(v8s*)&Af[cur ^ 1][0][smt][sfl * 8] = hi;
            *(v8s*)&Af[cur ^ 1][1][smt][sfl * 8] = lo;
        }
        __syncthreads();
    };

    for (int st2 = 0; st2 < 16; st2 += 2) {
        step(st2,     whA, wlA, whB, wlB);
        step(st2 + 1, whB, wlB, whA, wlA);
    }

    const int krow0 = wv * 32;
    if (p == 0) {
        float* outp = PpartK + ((size_t)sc * B_ + b) * (KP_ * D_);
#pragma unroll
        for (int i = 0; i < 2; ++i)
#pragma unroll
            for (int m = 0; m < 4; ++m)
#pragma unroll
                for (int r = 0; r < 4; ++r) {
                    int k = krow0 + i * 16 + (l >> 4) * 4 + r;
                    int d = m * 16 + (l & 15);
                    outp[(size_t)k * D_ + d] = acc[i][m][r];
                }
    } else {
        float* outp = PpartV + ((size_t)sc * B_ + b) * (KP_ * D_);
#pragma unroll
        for (int i = 0; i < 2; ++i)
#pragma unroll
            for (int m = 0; m < 4; ++m)
#pragma unroll
                for (int r = 0; r < 4; ++r) {
                    int d = m * 16 + (l >> 4) * 4 + r;
                    int k = krow0 + i * 16 + (l & 15);
                    outp[(size_t)d * KP_ + k] = acc[i][m][r];
                }
    }
}

// ---------------------------------------------------------------------------
// Kernel 3: reduce partials + bias -> bf16 planes, frag-contiguous. (R5 exact)
// ---------------------------------------------------------------------------
__global__ __launch_bounds__(256)
void reduce_kernel(const float* __restrict__ PpartK, const float* __restrict__ PpartV,
                   const float* __restrict__ E_b, const float* __restrict__ F_b,
                   short* __restrict__ Kp_hi, short* __restrict__ Kp_lo,
                   short* __restrict__ Vp_hi)
{
    const int j    = blockIdx.x * 256 + threadIdx.x;   // 0..131071
    const int side = j >> 16;                          // block-uniform
    const int i4   = j & 65535;
    const int flat = i4 * 4;                           // b*16384 + dk
    const int b    = flat >> 14;
    const int dk   = flat & 16383;

    if (side == 0) {
        float4 a = make_float4(0.f, 0.f, 0.f, 0.f);
#pragma unroll
        for (int sc = 0; sc < 8; ++sc) {
            float4 v = *(const float4*)(PpartK + ((size_t)sc * B_ + b) * (KP_ * D_) + dk);
            a.x += v.x; a.y += v.y; a.z += v.z; a.w += v.w;
        }
        const int k = dk >> 6, d = dk & 63;            // d % 4 == 0
        float be = E_b[k];
        a.x += be; a.y += be; a.z += be; a.w += be;
        short4 h, lo;
        h.x = f2bf(a.x); lo.x = f2bf(a.x - bf2f(h.x));
        h.y = f2bf(a.y); lo.y = f2bf(a.y - bf2f(h.y));
        h.z = f2bf(a.z); lo.z = f2bf(a.z - bf2f(h.z));
        h.w = f2bf(a.w); lo.w = f2bf(a.w - bf2f(h.w));
        const size_t fo = (((size_t)b * 2 + (d >> 5)) * 16 + (k >> 4)) * 512
                        + (size_t)((k & 15) + ((d >> 3) & 3) * 16) * 8 + (d & 7);
        *(short4*)(Kp_hi + fo) = h;
        *(short4*)(Kp_lo + fo) = lo;
    } else {
        float4 a = make_float4(0.f, 0.f, 0.f, 0.f);
#pragma unroll
        for (int sc = 0; sc < 8; ++sc) {
            float4 v = *(const float4*)(PpartV + ((size_t)sc * B_ + b) * (KP_ * D_) + dk);
            a.x += v.x; a.y += v.y; a.z += v.z; a.w += v.w;
        }
        const int d = dk >> 8, k = dk & 255;           // k % 4 == 0
        float4 bf = *(const float4*)(F_b + k);
        a.x += bf.x; a.y += bf.y; a.z += bf.z; a.w += bf.w;
        short4 h;
        h.x = f2bf(a.x); h.y = f2bf(a.y); h.z = f2bf(a.z); h.w = f2bf(a.w);
        const size_t fo = (((size_t)b * 8 + (k >> 5)) * 4 + (d >> 4)) * 512
                        + (size_t)((d & 15) + ((k >> 3) & 3) * 16) * 8 + (k & 7);
        *(short4*)(Vp_hi + fo) = h;
    }
}

// ---------------------------------------------------------------------------
// Kernel 4: scores -> softmax -> attn write -> out, rescheduled staging.
// grid (64 st, 16 b) x 256 thr (4 waves). LDS 50688 B (3 blk/CU).
// Regions: smem[0:16KB] = Qf, then kd1-hi buf (KH1), then Pl rows 0..30;
//          smem[16KB:32KB] = kd0-lo buf (KLl), then Pl rows 31..63;
//          Fst 16.9KB = kd0-hi buf (KLh), softmax store staging, V buf.
// ---------------------------------------------------------------------------
__global__ __launch_bounds__(256, 3)
void attn_mfma_kernel(const float* __restrict__ Qg,
                      const short* __restrict__ Kp_hi, const short* __restrict__ Kp_lo,
                      const short* __restrict__ Vp_hi,
                      float* __restrict__ attn_out, float* __restrict__ outg)
{
    const int st = blockIdx.x;
    const int b  = blockIdx.y;
    const int t  = threadIdx.x;
    const int wv = t >> 6;
    const int l  = t & 63;

    __shared__ __align__(16) short smem[64 * 264];
    __shared__ __align__(16) float Fst[4][4][264];
    short (*Qf)[2][4][512] = (short (*)[2][4][512])smem;   // [kd][plane][mt][fl*8]
    short* Pl  = smem;                                 // attn tile, pitch 264
    short* KLl = smem + 8192;                          // kd0-lo staging (16KB)
    short* KH1 = smem;                                 // kd1-hi staging (ex-Qf)
    short* KLh = (short*)&Fst[0][0][0];                // kd0-hi staging (16KB)

    const size_t tb = (size_t)b * 16384;               // kd0 table base (shorts)

    // (1) issue kd0 Kp hi/lo loads -> regs (no barrier before the LDS write,
    //     so latency hides under the Q f2bf VALU work below)
    int4 c0h[4], c0l[4];
    {
        const int4* gh = (const int4*)(Kp_hi + tb);
        const int4* gl = (const int4*)(Kp_lo + tb);
#pragma unroll
        for (int i = 0; i < 4; ++i) { c0h[i] = gh[t + i * 256]; c0l[i] = gl[t + i * 256]; }
    }

    // (2) Q fragment staging (hi/lo) — VALU-heavy, covers (1)
    {
        const int s    = t & 63;
        const int doct = t >> 6;
        const float* qrow = Qg + ((size_t)b * S_ + st * 64 + s) * D_;
        const int mt = s >> 4, fl = (s & 15) + doct * 16;
#pragma unroll
        for (int kd = 0; kd < 2; ++kd) {
            float4 v0 = *(const float4*)(qrow + kd * 32 + doct * 8);
            float4 v1 = *(const float4*)(qrow + kd * 32 + doct * 8 + 4);
            float gq[8] = {v0.x, v0.y, v0.z, v0.w, v1.x, v1.y, v1.z, v1.w};
            v8s hi, lo;
#pragma unroll
            for (int jj = 0; jj < 8; ++jj) { short h = f2bf(gq[jj]); hi[jj] = h; lo[jj] = f2bf(gq[jj] - bf2f(h)); }
            *(v8s*)&Qf[kd][0][mt][fl * 8] = hi;
            *(v8s*)&Qf[kd][1][mt][fl * 8] = lo;
        }
    }
    // (3) write kd0 staging to LDS
    {
        int4* lh = (int4*)KLh; int4* ll = (int4*)KLl;
#pragma unroll
        for (int i = 0; i < 4; ++i) { lh[t + i * 256] = c0h[i]; ll[t + i * 256] = c0l[i]; }
    }
    __syncthreads();                                   // (4) Qf + kd0 bufs ready

    // (5) hoist A-fragments for BOTH kd to regs (frees Qf region)
    v8s Ah0 = *(const v8s*)&Qf[0][0][wv][l * 8];
    v8s Al0 = *(const v8s*)&Qf[0][1][wv][l * 8];
    v8s Ah1 = *(const v8s*)&Qf[1][0][wv][l * 8];
    v8s Al1 = *(const v8s*)&Qf[1][1][wv][l * 8];
    __syncthreads();                                   // (6) all waves done with Qf

    // (7) issue kd1-hi loads AFTER the barrier (no drain) -> covered by (8)
    int4 c1[4];
    {
        const int4* gh1 = (const int4*)(Kp_hi + tb + 8192);
#pragma unroll
        for (int i = 0; i < 4; ++i) c1[i] = gh1[t + i * 256];
    }

    // (8) kd0 score MFMAs (48)
    v4f acc2[16];
#pragma unroll
    for (int nt = 0; nt < 16; ++nt) acc2[nt] = (v4f){0.f, 0.f, 0.f, 0.f};
#pragma unroll
    for (int nt = 0; nt < 16; ++nt) {
        v8s Bh = *(const v8s*)&KLh[nt * 512 + l * 8];
        v8s Bl = *(const v8s*)&KLl[nt * 512 + l * 8];
        acc2[nt] = __builtin_amdgcn_mfma_f32_16x16x32_bf16(Ah0, Bh, acc2[nt], 0, 0, 0);
        acc2[nt] = __builtin_amdgcn_mfma_f32_16x16x32_bf16(Al0, Bh, acc2[nt], 0, 0, 0);
        acc2[nt] = __builtin_amdgcn_mfma_f32_16x16x32_bf16(Ah0, Bl, acc2[nt], 0, 0, 0);
    }
    // (9) write kd1-hi to KH1 (vmcnt wait for c1 was covered by (8))
    {
        int4* lh1 = (int4*)KH1;
#pragma unroll
        for (int i = 0; i < 4; ++i) lh1[t + i * 256] = c1[i];
    }
    __syncthreads();                                   // (10)

    // (11) kd1 score MFMAs: Bh from LDS, Bl direct from L2 (dense 1KB/wave,
    //      pipelined with the MFMAs)
    {
        const short* gl1 = Kp_lo + tb + 8192;
#pragma unroll
        for (int nt = 0; nt < 16; ++nt) {
            v8s Bh = *(const v8s*)&KH1[nt * 512 + l * 8];
            v8s Bl = *(const v8s*)(gl1 + (size_t)nt * 512 + (size_t)l * 8);
            acc2[nt] = __builtin_amdgcn_mfma_f32_16x16x32_bf16(Ah1, Bh, acc2[nt], 0, 0, 0);
            acc2[nt] = __builtin_amdgcn_mfma_f32_16x16x32_bf16(Al1, Bh, acc2[nt], 0, 0, 0);
            acc2[nt] = __builtin_amdgcn_mfma_f32_16x16x32_bf16(Ah1, Bl, acc2[nt], 0, 0, 0);
        }
    }
    __syncthreads();                                   // (12) LDS free for Pl/Fst

    // V batch 0: issue now, completes during softmax
    int4 vstg[4];
    {
        const int4* gv = (const int4*)(Vp_hi + tb);
#pragma unroll
        for (int i = 0; i < 4; ++i) vstg[i] = gv[t + i * 256];
    }

    // softmax per row (C layout: row = wv*16 + (l>>4)*4 + r, col = nt*16 + (l&15))
    const float scale = 0.125f;   // 1/sqrt(64)
    float* attn_b = attn_out + ((size_t)b * S_ + st * 64) * KP_;
    const int g = l >> 4;
#pragma unroll
    for (int r = 0; r < 4; ++r) {
        float m = -3.4e38f;
#pragma unroll
        for (int nt = 0; nt < 16; ++nt) m = fmaxf(m, acc2[nt][r]);
        m = fmaxf(m, __shfl_xor(m, 1));
        m = fmaxf(m, __shfl_xor(m, 2));
        m = fmaxf(m, __shfl_xor(m, 4));
        m = fmaxf(m, __shfl_xor(m, 8));
        float sum = 0.f;
#pragma unroll
        for (int nt = 0; nt < 16; ++nt) {
            float e = __expf((acc2[nt][r] - m) * scale);
            acc2[nt][r] = e; sum += e;
        }
        sum += __shfl_xor(sum, 1);
        sum += __shfl_xor(sum, 2);
        sum += __shfl_xor(sum, 4);
        sum += __shfl_xor(sum, 8);
        const float inv = 1.f / sum;
        const int s_loc = wv * 16 + g * 4 + r;
#pragma unroll
        for (int nt = 0; nt < 16; ++nt) {
            float pv = acc2[nt][r] * inv;
            Fst[wv][g][nt * 16 + (l & 15)] = pv;               // f32 for coalesced store
            Pl[s_loc * 264 + nt * 16 + (l & 15)] = f2bf(pv);   // bf16 for PV
        }
        // coalesced attn store: dense 1KB rows (same-wave LDS RAW)
#pragma unroll
        for (int gg = 0; gg < 4; ++gg) {
            float4 vv = *(const float4*)&Fst[wv][gg][l * 4];
            *(float4*)(attn_b + (size_t)(wv * 16 + gg * 4 + r) * KP_ + l * 4) = vv;
        }
    }
    __syncthreads();                                   // Fst free (batch0 done)
    {   // write V batch 0 into KLh (= Fst region)
        int4* lv = (int4*)KLh;
#pragma unroll
        for (int i = 0; i < 4; ++i) lv[t + i * 256] = vstg[i];
    }
    __syncthreads();                                   // KLh visible
    // issue V batch 1 AFTER the barrier -> covered by PV half 1
    {
        const int4* gv2 = (const int4*)(Vp_hi + tb + 8192);
#pragma unroll
        for (int i = 0; i < 4; ++i) vstg[i] = gv2[t + i * 256];
    }
    // PV half 1
    v4f acc3[4];
#pragma unroll
    for (int nt = 0; nt < 4; ++nt) acc3[nt] = (v4f){0.f, 0.f, 0.f, 0.f};
#pragma unroll
    for (int kc = 0; kc < 4; ++kc) {
        v8s A3 = *(const v8s*)&Pl[(wv * 16 + (l & 15)) * 264 + kc * 32 + (l >> 4) * 8];
#pragma unroll
        for (int nt = 0; nt < 4; ++nt) {
            v8s B3 = *(const v8s*)&KLh[(kc * 4 + nt) * 512 + l * 8];
            acc3[nt] = __builtin_amdgcn_mfma_f32_16x16x32_bf16(A3, B3, acc3[nt], 0, 0, 0);
        }
    }
    __syncthreads();                                   // all PV1 reads done
    {   // write V batch 1
        int4* lv = (int4*)KLh;
#pragma unroll
        for (int i = 0; i < 4; ++i) lv[t + i * 256] = vstg[i];
    }
    __syncthreads();
#pragma unroll
    for (int kc = 4; kc < 8; ++kc) {
        v8s A3 = *(const v8s*)&Pl[(wv * 16 + (l & 15)) * 264 + kc * 32 + (l >> 4) * 8];
#pragma unroll
        for (int nt = 0; nt < 4; ++nt) {
            v8s B3 = *(const v8s*)&KLh[((kc - 4) * 4 + nt) * 512 + l * 8];
            acc3[nt] = __builtin_amdgcn_mfma_f32_16x16x32_bf16(A3, B3, acc3[nt], 0, 0, 0);
        }
    }
    float* out_b = outg + ((size_t)b * S_ + st * 64) * D_;
#pragma unroll
    for (int nt = 0; nt < 4; ++nt)
#pragma unroll
        for (int r = 0; r < 4; ++r) {
            int s_loc = wv * 16 + (l >> 4) * 4 + r;
            out_b[(size_t)s_loc * D_ + nt * 16 + (l & 15)] = acc3[nt][r];
        }
}

extern "C" void kernel_launch(void* const* d_in, const int* in_sizes, int n_in,
                              void* d_out, int out_size, void* d_ws, size_t ws_size,
                              hipStream_t stream) {
    const float* Q   = (const float*)d_in[0];
    const float* K   = (const float*)d_in[1];
    const float* V   = (const float*)d_in[2];
    const float* E_w = (const float*)d_in[3];
    const float* E_b = (const float*)d_in[4];
    const float* F_w = (const float*)d_in[5];
    const float* F_b = (const float*)d_in[6];

    float* out  = (float*)d_out;                        // [B,S,D]
    float* attn = out + (size_t)B_ * S_ * D_;           // [B,S,KP]

    // ws: bf16 planes (9.5 MB total)
    short* Whi   = (short*)d_ws;                        // [2][KP][S] frag-tile, 4 MB
    short* Wlo   = Whi + (size_t)2 * KP_ * S_;          // 4 MB
    short* Kp_hi = Wlo + (size_t)2 * KP_ * S_;          // frag-order, 512 KB
    short* Kp_lo = Kp_hi + (size_t)B_ * KP_ * D_;
    short* Vp_hi = Kp_lo + (size_t)B_ * KP_ * D_;       // frag-order

    // partials live in the attn output region (dead until attn_mfma_kernel)
    float* PpartK = attn;                               // [8][B][KP*D]  8 MB
    float* PpartV = attn + (size_t)8 * B_ * KP_ * D_;   // [8][B][KP*D]  8 MB

    wcvt_kernel<<<dim3(KP_ * S_ / 4 / 256, 2), 256, 0, stream>>>(E_w, F_w, Whi, Wlo);
    proj_mfma_kernel<<<dim3(8, 2, B_), 512, 0, stream>>>(K, V, Whi, Wlo, PpartK, PpartV);
    reduce_kernel<<<dim3(512), 256, 0, stream>>>(PpartK, PpartV, E_b, F_b, Kp_hi, Kp_lo, Vp_hi);
    attn_mfma_kernel<<<dim3(S_ / 64, B_), 256, 0, stream>>>(Q, Kp_hi, Kp_lo, Vp_hi, attn, out);
}

// Round 10
// 183.016 us; speedup vs baseline: 1.0404x; 1.0404x over previous
//
#include <hip/hip_runtime.h>

// Linformer head, MFMA bf16-split rewrite. B=16, S=4096, D=64, KP=256.
// R5 config EXACT (best measured: 179.4us). Confirmation re-run.
// History: R3 frag-contiguous tables+coalesced stores (200.1); R4 attn LDS
// staging (183.8); R5 wcvt frag-tile W + proj reg-dbuf + V restage (179.4);
// R6/R8 proj restructures + async-V attn (189.5-189.6, REVERTED); R9 attn
// reschedule w/ reg-staging + direct-L2 Bl (190.4, REVERTED - reg pressure +
// per-wave L2 in MFMA chain; serial LDS staging at low VGPR wins at 3 blk/CU).

#define B_  16
#define S_  4096
#define D_  64
#define KP_ 256

typedef short v8s __attribute__((ext_vector_type(8)));
typedef float v4f __attribute__((ext_vector_type(4)));

__device__ __forceinline__ short f2bf(float x) {        // RNE f32 -> bf16
    union { float f; unsigned u; } v; v.f = x;
    unsigned r = v.u + 0x7FFFu + ((v.u >> 16) & 1u);
    return (short)(r >> 16);
}
__device__ __forceinline__ float bf2f(short h) {
    union { float f; unsigned u; } v; v.u = ((unsigned)(unsigned short)h) << 16;
    return v.f;
}

// ---------------------------------------------------------------------------
// Kernel 1: W fp32 -> bf16 hi/lo planes in FRAG-TILE order. grid (1024,2)x256.
// Tile (p, k16=k>>4, sb=s>>5) of 512 shorts; within tile:
//   lane = (k&15) + ((s>>3)&3)*16, elem = s&7  ->  off = tile*512 + lane*8 + elem
// Matches proj wave load: off = ((p*16 + k16 + i)*128 + sc*16 + st)*512 + l*8.
// ---------------------------------------------------------------------------
__global__ __launch_bounds__(256)
void wcvt_kernel(const float* __restrict__ E_w, const float* __restrict__ F_w,
                 short* __restrict__ Whi, short* __restrict__ Wlo)
{
    const int p = blockIdx.y;
    const float* W = p ? F_w : E_w;
    const size_t i4 = (size_t)blockIdx.x * 256 + threadIdx.x;   // float4 idx
    float4 v = ((const float4*)W)[i4];
    short4 h, lo;
    h.x = f2bf(v.x); lo.x = f2bf(v.x - bf2f(h.x));
    h.y = f2bf(v.y); lo.y = f2bf(v.y - bf2f(h.y));
    h.z = f2bf(v.z); lo.z = f2bf(v.z - bf2f(h.z));
    h.w = f2bf(v.w); lo.w = f2bf(v.w - bf2f(h.w));
    const int k  = (int)(i4 >> 10);            // S/4 = 1024 float4 per k-row
    const int s0 = (int)(i4 & 1023) << 2;      // s0 % 4 == 0 -> same 8-block
    const size_t fo = (((size_t)p * 16 + (k >> 4)) * 128 + (s0 >> 5)) * 512
                    + (size_t)(((k & 15) + ((s0 >> 3) & 3) * 16) * 8) + (s0 & 7);
    *(short4*)(Whi + fo) = h;
    *(short4*)(Wlo + fo) = lo;
}

// ---------------------------------------------------------------------------
// Kernel 2: projections via MFMA, split-S partials.
// grid (sc 8, p 2, b 16) x 512 thr (8 waves). W loads frag-tile dense +
// register double-buffered (prefetch next st). Partial store layout unchanged.
// ---------------------------------------------------------------------------
__global__ __launch_bounds__(512, 2)
void proj_mfma_kernel(const float* __restrict__ Kg, const float* __restrict__ Vg,
                      const short* __restrict__ Whi, const short* __restrict__ Wlo,
                      float* __restrict__ PpartK, float* __restrict__ PpartV)
{
    const int sc = blockIdx.x;     // s-chunk of 512
    const int p  = blockIdx.y;     // 0 -> Kp, 1 -> Vp
    const int b  = blockIdx.z;

    const float* src = (p ? Vg : Kg) + ((size_t)b * S_ + sc * 512) * D_;

    __shared__ __align__(16) short Af[2][2][4][512];  // [buf][plane][mt=d/16][fraglane*8] 16KB

    const int t  = threadIdx.x;
    const int wv = t >> 6;
    const int l  = t & 63;
    const int k16 = wv * 2;        // wave's base k16 tile

    // W frag-tile offset for (i, st): dense per-wave 1KB
    const size_t wbase = ((size_t)p * 16 + k16) * 128 * 512 + (size_t)(sc * 16) * 512 + (size_t)l * 8;
    // off(i, st) = wbase + i*128*512 + st*512

    v4f acc[2][4];
#pragma unroll
    for (int i = 0; i < 2; ++i)
#pragma unroll
        for (int m = 0; m < 4; ++m) acc[i][m] = (v4f){0.f, 0.f, 0.f, 0.f};

    const bool do_stage = (t < 256);
    const int sd   = t & 63;
    const int soct = (t >> 6) & 3;
    const int smt  = sd >> 4;
    const int sfl  = (sd & 15) + soct * 16;

    // issue first W loads early (independent of LDS)
    v8s whA[2], wlA[2], whB[2], wlB[2];
#pragma unroll
    for (int i = 0; i < 2; ++i) {
        size_t o = wbase + (size_t)i * 65536;
        whA[i] = *(const v8s*)(Whi + o);
        wlA[i] = *(const v8s*)(Wlo + o);
    }

    float g[8];
    if (do_stage) {
        const float* sp = src + (size_t)(soct * 8) * D_ + sd;
#pragma unroll
        for (int j = 0; j < 8; ++j) g[j] = sp[(size_t)j * D_];
        v8s hi, lo;
#pragma unroll
        for (int j = 0; j < 8; ++j) { short h = f2bf(g[j]); hi[j] = h; lo[j] = f2bf(g[j] - bf2f(h)); }
        *(v8s*)&Af[0][0][smt][sfl * 8] = hi;
        *(v8s*)&Af[0][1][smt][sfl * 8] = lo;
    }
    __syncthreads();

    auto step = [&](int st, v8s (&whc)[2], v8s (&wlc)[2], v8s (&whn)[2], v8s (&wln)[2]) {
        const int cur = st & 1;
        if (st + 1 < 16) {
            // prefetch next-st W fragments (dense 1KB/wave each)
#pragma unroll
            for (int i = 0; i < 2; ++i) {
                size_t o = wbase + (size_t)i * 65536 + (size_t)(st + 1) * 512;
                whn[i] = *(const v8s*)(Whi + o);
                wln[i] = *(const v8s*)(Wlo + o);
            }
            if (do_stage) {      // prefetch next-st src
                const float* sp = src + (size_t)((st + 1) * 32 + soct * 8) * D_ + sd;
#pragma unroll
                for (int j = 0; j < 8; ++j) g[j] = sp[(size_t)j * D_];
            }
        }
        // src fragments (LDS, fragment order: lane reads its own 16B)
        v8s sh[4], sl[4];
#pragma unroll
        for (int m = 0; m < 4; ++m) {
            sh[m] = *(const v8s*)&Af[cur][0][m][l * 8];
            sl[m] = *(const v8s*)&Af[cur][1][m][l * 8];
        }
        if (p == 0) {       // C[k,d] = W @ src : A=W, B=src
#pragma unroll
            for (int i = 0; i < 2; ++i)
#pragma unroll
                for (int m = 0; m < 4; ++m) {
                    acc[i][m] = __builtin_amdgcn_mfma_f32_16x16x32_bf16(whc[i], sh[m], acc[i][m], 0, 0, 0);
                    acc[i][m] = __builtin_amdgcn_mfma_f32_16x16x32_bf16(whc[i], sl[m], acc[i][m], 0, 0, 0);
                    acc[i][m] = __builtin_amdgcn_mfma_f32_16x16x32_bf16(wlc[i], sh[m], acc[i][m], 0, 0, 0);
                }
        } else {            // C'[d,k] = src^T @ W^T : A=src, B=W
#pragma unroll
            for (int i = 0; i < 2; ++i)
#pragma unroll
                for (int m = 0; m < 4; ++m) {
                    acc[i][m] = __builtin_amdgcn_mfma_f32_16x16x32_bf16(sh[m], whc[i], acc[i][m], 0, 0, 0);
                    acc[i][m] = __builtin_amdgcn_mfma_f32_16x16x32_bf16(sl[m], whc[i], acc[i][m], 0, 0, 0);
                    acc[i][m] = __builtin_amdgcn_mfma_f32_16x16x32_bf16(sh[m], wlc[i], acc[i][m], 0, 0, 0);
                }
        }
        if (st + 1 < 16 && do_stage) {      // convert + write next buffer
            v8s hi, lo;
#pragma unroll
            for (int j = 0; j < 8; ++j) { short h = f2bf(g[j]); hi[j] = h; lo[j] = f2bf(g[j] - bf2f(h)); }
            *(v8s*)&Af[cur ^ 1][0][smt][sfl * 8] = hi;
            *(v8s*)&Af[cur ^ 1][1][smt][sfl * 8] = lo;
        }
        __syncthreads();
    };

    for (int st2 = 0; st2 < 16; st2 += 2) {
        step(st2,     whA, wlA, whB, wlB);
        step(st2 + 1, whB, wlB, whA, wlA);
    }

    const int krow0 = wv * 32;
    if (p == 0) {
        float* outp = PpartK + ((size_t)sc * B_ + b) * (KP_ * D_);
#pragma unroll
        for (int i = 0; i < 2; ++i)
#pragma unroll
            for (int m = 0; m < 4; ++m)
#pragma unroll
                for (int r = 0; r < 4; ++r) {
                    int k = krow0 + i * 16 + (l >> 4) * 4 + r;
                    int d = m * 16 + (l & 15);
                    outp[(size_t)k * D_ + d] = acc[i][m][r];
                }
    } else {
        float* outp = PpartV + ((size_t)sc * B_ + b) * (KP_ * D_);
#pragma unroll
        for (int i = 0; i < 2; ++i)
#pragma unroll
            for (int m = 0; m < 4; ++m)
#pragma unroll
                for (int r = 0; r < 4; ++r) {
                    int d = m * 16 + (l >> 4) * 4 + r;
                    int k = krow0 + i * 16 + (l & 15);
                    outp[(size_t)d * KP_ + k] = acc[i][m][r];
                }
    }
}

// ---------------------------------------------------------------------------
// Kernel 3: reduce partials + bias -> bf16 planes, FRAGMENT-CONTIGUOUS order.
// ---------------------------------------------------------------------------
__global__ __launch_bounds__(256)
void reduce_kernel(const float* __restrict__ PpartK, const float* __restrict__ PpartV,
                   const float* __restrict__ E_b, const float* __restrict__ F_b,
                   short* __restrict__ Kp_hi, short* __restrict__ Kp_lo,
                   short* __restrict__ Vp_hi)
{
    const int j    = blockIdx.x * 256 + threadIdx.x;   // 0..131071
    const int side = j >> 16;                          // block-uniform
    const int i4   = j & 65535;
    const int flat = i4 * 4;                           // b*16384 + dk
    const int b    = flat >> 14;
    const int dk   = flat & 16383;

    if (side == 0) {
        float4 a = make_float4(0.f, 0.f, 0.f, 0.f);
#pragma unroll
        for (int sc = 0; sc < 8; ++sc) {
            float4 v = *(const float4*)(PpartK + ((size_t)sc * B_ + b) * (KP_ * D_) + dk);
            a.x += v.x; a.y += v.y; a.z += v.z; a.w += v.w;
        }
        const int k = dk >> 6, d = dk & 63;            // d % 4 == 0
        float be = E_b[k];
        a.x += be; a.y += be; a.z += be; a.w += be;
        short4 h, lo;
        h.x = f2bf(a.x); lo.x = f2bf(a.x - bf2f(h.x));
        h.y = f2bf(a.y); lo.y = f2bf(a.y - bf2f(h.y));
        h.z = f2bf(a.z); lo.z = f2bf(a.z - bf2f(h.z));
        h.w = f2bf(a.w); lo.w = f2bf(a.w - bf2f(h.w));
        const size_t fo = (((size_t)b * 2 + (d >> 5)) * 16 + (k >> 4)) * 512
                        + (size_t)((k & 15) + ((d >> 3) & 3) * 16) * 8 + (d & 7);
        *(short4*)(Kp_hi + fo) = h;
        *(short4*)(Kp_lo + fo) = lo;
    } else {
        float4 a = make_float4(0.f, 0.f, 0.f, 0.f);
#pragma unroll
        for (int sc = 0; sc < 8; ++sc) {
            float4 v = *(const float4*)(PpartV + ((size_t)sc * B_ + b) * (KP_ * D_) + dk);
            a.x += v.x; a.y += v.y; a.z += v.z; a.w += v.w;
        }
        const int d = dk >> 8, k = dk & 255;           // k % 4 == 0
        float4 bf = *(const float4*)(F_b + k);
        a.x += bf.x; a.y += bf.y; a.z += bf.z; a.w += bf.w;
        short4 h;
        h.x = f2bf(a.x); h.y = f2bf(a.y); h.z = f2bf(a.z); h.w = f2bf(a.w);
        const size_t fo = (((size_t)b * 8 + (k >> 5)) * 4 + (d >> 4)) * 512
                        + (size_t)((d & 15) + ((k >> 3) & 3) * 16) * 8 + (k & 7);
        *(short4*)(Vp_hi + fo) = h;
    }
}

// ---------------------------------------------------------------------------
// Kernel 4: scores -> softmax -> attn write -> out, all MFMA.
// grid (64 st, 16 b) x 256 thr (4 waves). LDS 50688 B, regions time-shared.
// PV second half (kc4-7) restaged into KLh after kc0-3 consumed.
// ---------------------------------------------------------------------------
__global__ __launch_bounds__(256, 3)
void attn_mfma_kernel(const float* __restrict__ Qg,
                      const short* __restrict__ Kp_hi, const short* __restrict__ Kp_lo,
                      const short* __restrict__ Vp_hi,
                      float* __restrict__ attn_out, float* __restrict__ outg)
{
    const int st = blockIdx.x;
    const int b  = blockIdx.y;
    const int t  = threadIdx.x;
    const int wv = t >> 6;
    const int l  = t & 63;

    __shared__ __align__(16) short smem[64 * 264];     // union: Qf+KLl / Pl
    __shared__ __align__(16) float Fst[4][4][264];     // union: KLh / store staging / VL
    short (*Qf)[2][4][512] = (short (*)[2][4][512])smem;   // [kd][plane][mt][fraglane*8]
    short* Pl  = smem;                                 // attn tile, pitch 264
    short* KLl = smem + 8192;                          // 16KB lo-plane staging
    short* KLh = (short*)&Fst[0][0][0];                // 16KB hi-plane staging

    {   // stage Q fragments (hi/lo)
        const int s    = t & 63;
        const int doct = t >> 6;
        const float* qrow = Qg + ((size_t)b * S_ + st * 64 + s) * D_;
        const int mt = s >> 4, fl = (s & 15) + doct * 16;
#pragma unroll
        for (int kd = 0; kd < 2; ++kd) {
            float4 v0 = *(const float4*)(qrow + kd * 32 + doct * 8);
            float4 v1 = *(const float4*)(qrow + kd * 32 + doct * 8 + 4);
            float gq[8] = {v0.x, v0.y, v0.z, v0.w, v1.x, v1.y, v1.z, v1.w};
            v8s hi, lo;
#pragma unroll
            for (int jj = 0; jj < 8; ++jj) { short h = f2bf(gq[jj]); hi[jj] = h; lo[jj] = f2bf(gq[jj] - bf2f(h)); }
            *(v8s*)&Qf[kd][0][mt][fl * 8] = hi;
            *(v8s*)&Qf[kd][1][mt][fl * 8] = lo;
        }
    }
    __syncthreads();

    // scores: C2[16 s x 256 k], 3-term split; B-operands LDS-staged per kd
    // (block-shared: stage once instead of 4 waves x same 32KB from L2)
    v4f acc2[16];
#pragma unroll
    for (int nt = 0; nt < 16; ++nt) acc2[nt] = (v4f){0.f, 0.f, 0.f, 0.f};
#pragma unroll
    for (int kd = 0; kd < 2; ++kd) {
        {   // cooperative copy: Kp_hi[kd] -> KLh, Kp_lo[kd] -> KLl (16KB each)
            const size_t tbl = (((size_t)b * 2 + kd) * 16) * 512;   // shorts
            const int4* gh = (const int4*)(Kp_hi + tbl);
            const int4* gl = (const int4*)(Kp_lo + tbl);
            int4* lh = (int4*)KLh;
            int4* ll = (int4*)KLl;
#pragma unroll
            for (int i = 0; i < 4; ++i) lh[t + i * 256] = gh[t + i * 256];
#pragma unroll
            for (int i = 0; i < 4; ++i) ll[t + i * 256] = gl[t + i * 256];
        }
        __syncthreads();
        v8s Ah = *(const v8s*)&Qf[kd][0][wv][l * 8];
        v8s Al = *(const v8s*)&Qf[kd][1][wv][l * 8];
#pragma unroll
        for (int nt = 0; nt < 16; ++nt) {
            v8s Bh = *(const v8s*)&KLh[nt * 512 + l * 8];
            v8s Bl = *(const v8s*)&KLl[nt * 512 + l * 8];
            acc2[nt] = __builtin_amdgcn_mfma_f32_16x16x32_bf16(Ah, Bh, acc2[nt], 0, 0, 0);
            acc2[nt] = __builtin_amdgcn_mfma_f32_16x16x32_bf16(Al, Bh, acc2[nt], 0, 0, 0);
            acc2[nt] = __builtin_amdgcn_mfma_f32_16x16x32_bf16(Ah, Bl, acc2[nt], 0, 0, 0);
        }
        __syncthreads();   // staging buffers reusable (next kd / Pl / Fst)
    }

    // softmax per row (C layout: row = wv*16 + (l>>4)*4 + r, col = nt*16 + (l&15))
    const float scale = 0.125f;   // 1/sqrt(64)
    float* attn_b = attn_out + ((size_t)b * S_ + st * 64) * KP_;
    const int g = l >> 4;
#pragma unroll
    for (int r = 0; r < 4; ++r) {
        float m = -3.4e38f;
#pragma unroll
        for (int nt = 0; nt < 16; ++nt) m = fmaxf(m, acc2[nt][r]);
        m = fmaxf(m, __shfl_xor(m, 1));
        m = fmaxf(m, __shfl_xor(m, 2));
        m = fmaxf(m, __shfl_xor(m, 4));
        m = fmaxf(m, __shfl_xor(m, 8));
        float sum = 0.f;
#pragma unroll
        for (int nt = 0; nt < 16; ++nt) {
            float e = __expf((acc2[nt][r] - m) * scale);
            acc2[nt][r] = e; sum += e;
        }
        sum += __shfl_xor(sum, 1);
        sum += __shfl_xor(sum, 2);
        sum += __shfl_xor(sum, 4);
        sum += __shfl_xor(sum, 8);
        const float inv = 1.f / sum;
        const int s_loc = wv * 16 + g * 4 + r;
#pragma unroll
        for (int nt = 0; nt < 16; ++nt) {
            float pv = acc2[nt][r] * inv;
            Fst[wv][g][nt * 16 + (l & 15)] = pv;               // f32 for coalesced store
            Pl[s_loc * 264 + nt * 16 + (l & 15)] = f2bf(pv);   // bf16 for PV
        }
        // coalesced attn store: one dense 1KB row per instr (same-wave LDS RAW)
#pragma unroll
        for (int gg = 0; gg < 4; ++gg) {
            float4 vv = *(const float4*)&Fst[wv][gg][l * 4];
            *(float4*)(attn_b + (size_t)(wv * 16 + gg * 4 + r) * KP_ + l * 4) = vv;
        }
    }
    // stage Vp kc0-3 (16KB) into Fst region (dead after attn stores)
    __syncthreads();
    {
        const int4* gv = (const int4*)(Vp_hi + (size_t)b * 16384);
        int4* lv = (int4*)KLh;
#pragma unroll
        for (int i = 0; i < 4; ++i) lv[t + i * 256] = gv[t + i * 256];
    }
    __syncthreads();
    // PV: rows wv*16..+16 of Pl written by this wave only
    v4f acc3[4];
#pragma unroll
    for (int nt = 0; nt < 4; ++nt) acc3[nt] = (v4f){0.f, 0.f, 0.f, 0.f};
#pragma unroll
    for (int kc = 0; kc < 4; ++kc) {
        v8s A3 = *(const v8s*)&Pl[(wv * 16 + (l & 15)) * 264 + kc * 32 + (l >> 4) * 8];
#pragma unroll
        for (int nt = 0; nt < 4; ++nt) {
            v8s B3 = *(const v8s*)&KLh[(kc * 4 + nt) * 512 + l * 8];
            acc3[nt] = __builtin_amdgcn_mfma_f32_16x16x32_bf16(A3, B3, acc3[nt], 0, 0, 0);
        }
    }
    // restage Vp kc4-7 into the same buffer
    __syncthreads();
    {
        const int4* gv = (const int4*)(Vp_hi + (size_t)b * 16384 + 8192);
        int4* lv = (int4*)KLh;
#pragma unroll
        for (int i = 0; i < 4; ++i) lv[t + i * 256] = gv[t + i * 256];
    }
    __syncthreads();
#pragma unroll
    for (int kc = 4; kc < 8; ++kc) {
        v8s A3 = *(const v8s*)&Pl[(wv * 16 + (l & 15)) * 264 + kc * 32 + (l >> 4) * 8];
#pragma unroll
        for (int nt = 0; nt < 4; ++nt) {
            v8s B3 = *(const v8s*)&KLh[((kc - 4) * 4 + nt) * 512 + l * 8];
            acc3[nt] = __builtin_amdgcn_mfma_f32_16x16x32_bf16(A3, B3, acc3[nt], 0, 0, 0);
        }
    }
    float* out_b = outg + ((size_t)b * S_ + st * 64) * D_;
#pragma unroll
    for (int nt = 0; nt < 4; ++nt)
#pragma unroll
        for (int r = 0; r < 4; ++r) {
            int s_loc = wv * 16 + (l >> 4) * 4 + r;
            out_b[(size_t)s_loc * D_ + nt * 16 + (l & 15)] = acc3[nt][r];
        }
}

extern "C" void kernel_launch(void* const* d_in, const int* in_sizes, int n_in,
                              void* d_out, int out_size, void* d_ws, size_t ws_size,
                              hipStream_t stream) {
    const float* Q   = (const float*)d_in[0];
    const float* K   = (const float*)d_in[1];
    const float* V   = (const float*)d_in[2];
    const float* E_w = (const float*)d_in[3];
    const float* E_b = (const float*)d_in[4];
    const float* F_w = (const float*)d_in[5];
    const float* F_b = (const float*)d_in[6];

    float* out  = (float*)d_out;                        // [B,S,D]
    float* attn = out + (size_t)B_ * S_ * D_;           // [B,S,KP]

    // ws: bf16 planes (9.5 MB total)
    short* Whi   = (short*)d_ws;                        // [2][KP][S] frag-tile, 4 MB
    short* Wlo   = Whi + (size_t)2 * KP_ * S_;          // 4 MB
    short* Kp_hi = Wlo + (size_t)2 * KP_ * S_;          // frag-order, 512 KB
    short* Kp_lo = Kp_hi + (size_t)B_ * KP_ * D_;
    short* Vp_hi = Kp_lo + (size_t)B_ * KP_ * D_;       // frag-order

    // partials live in the attn output region (dead until attn_mfma_kernel)
    float* PpartK = attn;                               // [8][B][KP*D]  8 MB
    float* PpartV = attn + (size_t)8 * B_ * KP_ * D_;   // [8][B][KP*D]  8 MB

    wcvt_kernel<<<dim3(KP_ * S_ / 4 / 256, 2), 256, 0, stream>>>(E_w, F_w, Whi, Wlo);
    proj_mfma_kernel<<<dim3(8, 2, B_), 512, 0, stream>>>(K, V, Whi, Wlo, PpartK, PpartV);
    reduce_kernel<<<dim3(512), 256, 0, stream>>>(PpartK, PpartV, E_b, F_b, Kp_hi, Kp_lo, Vp_hi);
    attn_mfma_kernel<<<dim3(S_ / 64, B_), 256, 0, stream>>>(Q, Kp_hi, Kp_lo, Vp_hi, attn, out);
}